// Round 2
// baseline (4861.942 us; speedup 1.0000x reference)
//
#include <hip/hip_runtime.h>
#include <stdint.h>
#include <stddef.h>

#define NTS 256

typedef short bf16x8 __attribute__((ext_vector_type(8)));
typedef short bf16x4 __attribute__((ext_vector_type(4)));
typedef float f32x4 __attribute__((ext_vector_type(4)));
typedef float f32x2 __attribute__((ext_vector_type(2)));

__device__ __forceinline__ unsigned short f2bf(float f) {
  union { float f; unsigned u; } c; c.f = f;
  unsigned u = c.u;
  u += 0x7fffu + ((u >> 16) & 1u);   // round-to-nearest-even
  return (unsigned short)(u >> 16);
}

// Fragment-ordered weight panels:
// wpF[pan(18)][fb(32)][lane(64)][e(8)] bf16, where
//   pan 0..1  -> W1 K-blocks,  pan 2..17 -> W2 K-blocks (pan-2)
//   value = W[k = pank*32 + (lane>>4)*8 + e][f = fb*16 + (lane&15)]
// A-fragment for (panel, fblock) is then a single linear lane*16B read.
__global__ __launch_bounds__(256) void prep_weights(const float* __restrict__ W1,
                                                    const float* __restrict__ W2,
                                                    unsigned short* __restrict__ wp) {
  int gid = blockIdx.x * 256 + threadIdx.x;
  if (gid >= 294912) return;
  int e = gid & 7, lane = (gid >> 3) & 63, fb = (gid >> 9) & 31, pan = gid >> 14;
  int q = lane >> 4, j = lane & 15, f = fb * 16 + j;
  float v;
  if (pan < 2) v = W1[(pan * 32 + q * 8 + e) * 512 + f];
  else         v = W2[((pan - 2) * 32 + q * 8 + e) * 512 + f];
  wp[gid] = f2bf(v);
}

// LDS map (bytes):
//   [0,     65536)  h1F  [ks(16)][nt(4)][lane(64)][8] bf16   (fragment order)
//   [65536, 81920)  histF 2 bufs x [p(2)][nt(4)][lane(64)][8] bf16
//   [81920, 86016)  piL  [8 waves][64 b][2] f32
//   [86016, 90112)  dwL  [k(16)][b(64)] f32
//   [90112, 90240)  xnbL bf16[64]
//   [90240, 92288)  b1L f32[512]
//   [92288, 94336)  b2L f32[512]
//   [94336, 98432)  w3L f32[512][2]
__global__ __launch_bounds__(512, 2) void po_fused(
    const float* __restrict__ dw, const float* __restrict__ x_init,
    const float* __restrict__ exp_arr, const float* __restrict__ b1,
    const float* __restrict__ b2, const float* __restrict__ W3,
    const float* __restrict__ b3, const unsigned short* __restrict__ wp,
    float* __restrict__ out) {
  extern __shared__ char smem[];
  char* const h1C = smem;
  char* const histC = smem + 65536;
  float* const piL = (float*)(smem + 81920);
  float* const dwL = (float*)(smem + 86016);
  unsigned short* const xnbL = (unsigned short*)(smem + 90112);
  float* const b1L = (float*)(smem + 90240);
  float* const b2L = (float*)(smem + 92288);
  float* const w3L = (float*)(smem + 94336);

  const int tid = threadIdx.x;
  const int lane = tid & 63;
  const int wv = tid >> 6;
  const int q = lane >> 4;
  const int j = lane & 15;
  const int wg = blockIdx.x;

  // ---------------- init ----------------
  b1L[tid] = b1[tid];
  b2L[tid] = b2[tid];
  w3L[tid] = W3[tid];
  w3L[tid + 512] = W3[tid + 512];

  {  // histF buf0 fill, fragment order: block tid <-> (p,nt,lane)
    int ntp = tid >> 6;               // p*4+nt
    int p0 = ntp >> 2, nt0 = ntp & 3;
    int b = nt0 * 16 + j, k0 = p0 * 32 + q * 8;
    const float* src = x_init + ((size_t)wg * 64 + b) * 64 + k0;
    bf16x8 v;
#pragma unroll
    for (int e = 0; e < 8; ++e) v[e] = (short)f2bf(src[e]);
    *(bf16x8*)(histC + tid * 16) = v;
  }

  float xreg = 0.f, yreg = 0.f, rreg = 0.f;   // live in wave 0 (tid<64) only
  if (tid < 64) {
    const float* row = x_init + ((size_t)wg * 64 + tid) * 64;
    float y0 = 0.f;
    for (int k = 0; k < 63; ++k) y0 += exp_arr[k] * row[1 + k];
    y0 = y0 * 0.04f + (1.f - __expf(-2.52f)) * row[0];  // GEOMETRIC_SUM
    xreg = row[63];
    yreg = y0;
    rreg = 0.f;
  }
  const float b30 = b3[0], b31 = b3[1];

  // W1 resident in registers: w1r[p][mt] = fragment (pan=p, fb=wv*4+mt)
  bf16x8 w1r[2][4];
#pragma unroll
  for (int p = 0; p < 2; ++p)
#pragma unroll
    for (int mt = 0; mt < 4; ++mt)
      w1r[p][mt] = *(const bf16x8*)(wp + (((size_t)p * 32 + wv * 4 + mt) * 64 + lane) * 8);

  __syncthreads();

  int hb = 0;
  f32x4 acc[4][4];

#pragma unroll 1
  for (int t = 0; t < NTS; ++t) {
    // ---- prefetch W2 panel 0 (pan=2) into regs; flies during L1 ----
    bf16x8 wcur[4], wnxt[4];
#pragma unroll
    for (int mt = 0; mt < 4; ++mt)
      wcur[mt] = *(const bf16x8*)(wp + ((2 * 32 + (size_t)(wv * 4 + mt)) * 64 + lane) * 8);

    // ---- dw tile staging every 16 steps ----
    if ((t & 15) == 0) {
      int b = tid >> 3, c = tid & 7;
      f32x2 v = *(const f32x2*)(dw + ((size_t)wg * 64 + b) * NTS + t + c * 2);
      dwL[(c * 2) * 64 + b] = v[0];
      dwL[(c * 2 + 1) * 64 + b] = v[1];
    }

    // ---- Layer 1: acc = W1 @ histT (K=64, 2 panels, all reg-resident) ----
#pragma unroll
    for (int mt = 0; mt < 4; ++mt)
#pragma unroll
      for (int nt = 0; nt < 4; ++nt) acc[mt][nt] = (f32x4){0.f, 0.f, 0.f, 0.f};
    const char* hcur = histC + hb * 8192;
#pragma unroll
    for (int p = 0; p < 2; ++p) {
      bf16x8 bfr[4];
#pragma unroll
      for (int nt = 0; nt < 4; ++nt)
        bfr[nt] = *(const bf16x8*)(hcur + ((p * 4 + nt) * 64 + lane) * 16);
#pragma unroll
      for (int mt = 0; mt < 4; ++mt)
#pragma unroll
        for (int nt = 0; nt < 4; ++nt)
          acc[mt][nt] = __builtin_amdgcn_mfma_f32_16x16x32_bf16(w1r[p][mt], bfr[nt],
                                                                acc[mt][nt], 0, 0, 0);
    }
    // h1 epilogue: relu(+b1) -> bf16 -> h1F fragment order
#pragma unroll
    for (int mt = 0; mt < 4; ++mt) {
      int f0 = wv * 64 + mt * 16 + q * 4;
      int wb = ((f0 >> 5) * 256 + ((f0 >> 3) & 3) * 16 + j) * 16 + (f0 & 7) * 2;
#pragma unroll
      for (int nt = 0; nt < 4; ++nt) {
        bf16x4 pk;
#pragma unroll
        for (int r = 0; r < 4; ++r)
          pk[r] = (short)f2bf(fmaxf(acc[mt][nt][r] + b1L[f0 + r], 0.f));
        *(bf16x4*)(h1C + wb + nt * 1024) = pk;
      }
    }
    __syncthreads();  // (1) h1F + dwL visible

    // ---- Layer 2: 16 K-panels, weights streamed L2->reg, no barriers ----
#pragma unroll
    for (int mt = 0; mt < 4; ++mt)
#pragma unroll
      for (int nt = 0; nt < 4; ++nt) acc[mt][nt] = (f32x4){0.f, 0.f, 0.f, 0.f};
#pragma unroll
    for (int ks = 0; ks < 16; ++ks) {
      if (ks < 15) {
#pragma unroll
        for (int mt = 0; mt < 4; ++mt)
          wnxt[mt] = *(const bf16x8*)(wp + (((size_t)(ks + 3) * 32 + wv * 4 + mt) * 64 + lane) * 8);
      }
      bf16x8 bfr[4];
#pragma unroll
      for (int nt = 0; nt < 4; ++nt)
        bfr[nt] = *(const bf16x8*)(h1C + ((ks * 4 + nt) * 64 + lane) * 16);
#pragma unroll
      for (int mt = 0; mt < 4; ++mt)
#pragma unroll
        for (int nt = 0; nt < 4; ++nt)
          acc[mt][nt] = __builtin_amdgcn_mfma_f32_16x16x32_bf16(wcur[mt], bfr[nt],
                                                                acc[mt][nt], 0, 0, 0);
      if (ks < 15) {
#pragma unroll
        for (int mt = 0; mt < 4; ++mt) wcur[mt] = wnxt[mt];
      }
    }

    // ---- Layer 3 folded: pi partials + cross-lane reduce ----
#pragma unroll
    for (int nt = 0; nt < 4; ++nt) {
      float p0a = 0.f, p1a = 0.f;
#pragma unroll
      for (int mt = 0; mt < 4; ++mt) {
        int f0 = wv * 64 + mt * 16 + q * 4;
#pragma unroll
        for (int r = 0; r < 4; ++r) {
          float v = fmaxf(acc[mt][nt][r] + b2L[f0 + r], 0.f);
          p0a += v * w3L[(f0 + r) * 2];
          p1a += v * w3L[(f0 + r) * 2 + 1];
        }
      }
      p0a += __shfl_xor(p0a, 16); p0a += __shfl_xor(p0a, 32);
      p1a += __shfl_xor(p1a, 16); p1a += __shfl_xor(p1a, 32);
      if (q == 0) {
        int b = nt * 16 + j;
        piL[(wv * 64 + b) * 2] = p0a;
        piL[(wv * 64 + b) * 2 + 1] = p1a;
      }
    }
    __syncthreads();  // (2) piL visible

    // ---- dynamics (wave 0) ----
    if (tid < 64) {
      float z0 = b30, z1 = b31;
#pragma unroll
      for (int w = 0; w < 8; ++w) {
        z0 += piL[(w * 64 + tid) * 2];
        z1 += piL[(w * 64 + tid) * 2 + 1];
      }
      float pi0 = 2.f / (1.f + __expf(-z0));
      float pi1 = 2.f / (1.f + __expf(-z1));
      float x = xreg, y = yreg;
      float disc = __expf(-0.004f * (float)t);
      float rv = fmaxf(pi0 * x, 0.f) + 1e-6f;
      rreg += (__logf(rv) * disc - fmaxf(-x, 0.f) * 100.f) * 0.04f;
      float dwv = dwL[(t & 15) * 64 + tid];
      float dxv = (0.06f * pi1 - pi0 + 0.02f) * x + 0.02f * y;
      float xn = x + dxv * 0.04f + 0.2f * x * pi1 * dwv;
      yreg = y * 0.960789439152323f + xn * 0.04f;   // exp(-DT*LAMBD)
      xreg = xn;
      xnbL[tid] = f2bf(xn);
    }
    __syncthreads();  // (3) xnbL visible

    // ---- hist shift in fragment order: new[b][k] = old[b][k+1], [63]=x_new ----
    {
      const char* hc = histC + hb * 8192;
      char* hn = histC + (hb ^ 1) * 8192;
      int ntp = tid >> 6;
      int pIdx = ntp >> 2;            // 0 or 1
      int b = (ntp & 3) * 16 + j;
      bf16x8 own = *(const bf16x8*)(hc + tid * 16);
      unsigned short last;
      if (q == 3 && pIdx == 1) {
        last = xnbL[b];
      } else {
        int idx2 = (q < 3) ? tid + 16 : tid + 208;  // next k-block, same (b)
        bf16x8 nx = *(const bf16x8*)(hc + idx2 * 16);
        last = (unsigned short)nx[0];
      }
      bf16x8 nw;
#pragma unroll
      for (int e = 0; e < 7; ++e) nw[e] = own[e + 1];
      nw[7] = (short)last;
      *(bf16x8*)(hn + tid * 16) = nw;
    }
    hb ^= 1;
    __syncthreads();  // (4) histF[next] visible
  }

  if (tid < 64) {
    float rw = rreg + __logf(fmaxf(xreg + 0.5f * yreg, 0.f) + 1e-6f) * 10.f * __expf(-1.024f);
    rw -= fmaxf(-xreg, 0.f) * 100.f;
    out[(size_t)wg * 64 + tid] = -rw;
  }
}

extern "C" void kernel_launch(void* const* d_in, const int* in_sizes, int n_in,
                              void* d_out, int out_size, void* d_ws, size_t ws_size,
                              hipStream_t stream) {
  const float* dw      = (const float*)d_in[0];
  const float* x_init  = (const float*)d_in[1];
  const float* exp_arr = (const float*)d_in[2];
  const float* W1      = (const float*)d_in[3];
  const float* b1      = (const float*)d_in[4];
  const float* W2      = (const float*)d_in[5];
  const float* b2      = (const float*)d_in[6];
  const float* W3      = (const float*)d_in[7];
  const float* b3      = (const float*)d_in[8];
  unsigned short* wp = (unsigned short*)d_ws;  // needs 576KB
  float* out = (float*)d_out;

  (void)hipFuncSetAttribute((const void*)po_fused,
                            hipFuncAttributeMaxDynamicSharedMemorySize, 160 * 1024);

  prep_weights<<<1152, 256, 0, stream>>>(W1, W2, wp);
  po_fused<<<256, 512, 98432, stream>>>(dw, x_init, exp_arr, b1, b2, W3, b3, wp, out);
}

// Round 3
// 4615.932 us; speedup vs baseline: 1.0533x; 1.0533x over previous
//
#include <hip/hip_runtime.h>
#include <stdint.h>
#include <stddef.h>

#define NTS 256

typedef short bf16x8 __attribute__((ext_vector_type(8)));
typedef short bf16x4 __attribute__((ext_vector_type(4)));
typedef float f32x4 __attribute__((ext_vector_type(4)));
typedef float f32x2 __attribute__((ext_vector_type(2)));

__device__ __forceinline__ unsigned short f2bf(float f) {
  union { float f; unsigned u; } c; c.f = f;
  unsigned u = c.u;
  u += 0x7fffu + ((u >> 16) & 1u);   // round-to-nearest-even
  return (unsigned short)(u >> 16);
}

// Fragment-ordered weight panels:
// wpF[pan(18)][fb(32)][lane(64)][e(8)] bf16, where
//   pan 0..1  -> W1 K-blocks,  pan 2..17 -> W2 K-blocks (pan-2)
//   value = W[k = pank*32 + (lane>>4)*8 + e][f = fb*16 + (lane&15)]
// A-fragment for (panel, fblock) is then a single linear lane*16B read.
__global__ __launch_bounds__(256) void prep_weights(const float* __restrict__ W1,
                                                    const float* __restrict__ W2,
                                                    unsigned short* __restrict__ wp) {
  int gid = blockIdx.x * 256 + threadIdx.x;
  if (gid >= 294912) return;
  int e = gid & 7, lane = (gid >> 3) & 63, fb = (gid >> 9) & 31, pan = gid >> 14;
  int q = lane >> 4, j = lane & 15, f = fb * 16 + j;
  float v;
  if (pan < 2) v = W1[(pan * 32 + q * 8 + e) * 512 + f];
  else         v = W2[((pan - 2) * 32 + q * 8 + e) * 512 + f];
  wp[gid] = f2bf(v);
}

// LDS map (bytes):
//   [0,     65536)  h1F  [ks(16)][nt(4)][lane(64)][8] bf16   (fragment order)
//   [65536, 81920)  histF 2 bufs x [p(2)][nt(4)][lane(64)][8] bf16
//   [81920, 86016)  piL  [8 waves][64 b][2] f32
//   [86016, 90112)  dwL  [k(16)][b(64)] f32
//   [90112, 90240)  xnbL bf16[64]
//   [90240, 92288)  b1L f32[512]
//   [92288, 94336)  b2L f32[512]
//   [94336, 98432)  w3L f32[512][2]
__global__ __launch_bounds__(512, 1) void po_fused(
    const float* __restrict__ dw, const float* __restrict__ x_init,
    const float* __restrict__ exp_arr, const float* __restrict__ b1,
    const float* __restrict__ b2, const float* __restrict__ W3,
    const float* __restrict__ b3, const unsigned short* __restrict__ wp,
    float* __restrict__ out) {
  extern __shared__ char smem[];
  char* const h1C = smem;
  char* const histC = smem + 65536;
  float* const piL = (float*)(smem + 81920);
  float* const dwL = (float*)(smem + 86016);
  unsigned short* const xnbL = (unsigned short*)(smem + 90112);
  float* const b1L = (float*)(smem + 90240);
  float* const b2L = (float*)(smem + 92288);
  float* const w3L = (float*)(smem + 94336);

  const int tid = threadIdx.x;
  const int lane = tid & 63;
  const int wv = tid >> 6;
  const int q = lane >> 4;
  const int j = lane & 15;
  const int wg = blockIdx.x;

  // ---------------- init ----------------
  b1L[tid] = b1[tid];
  b2L[tid] = b2[tid];
  w3L[tid] = W3[tid];
  w3L[tid + 512] = W3[tid + 512];

  {  // histF buf0 fill, fragment order: block tid <-> (p,nt,lane)
    int ntp = tid >> 6;               // p*4+nt
    int p0 = ntp >> 2, nt0 = ntp & 3;
    int b = nt0 * 16 + j, k0 = p0 * 32 + q * 8;
    const float* src = x_init + ((size_t)wg * 64 + b) * 64 + k0;
    bf16x8 v;
#pragma unroll
    for (int e = 0; e < 8; ++e) v[e] = (short)f2bf(src[e]);
    *(bf16x8*)(histC + tid * 16) = v;
  }

  float xreg = 0.f, yreg = 0.f, rreg = 0.f;   // live in wave 0 (tid<64) only
  if (tid < 64) {
    const float* row = x_init + ((size_t)wg * 64 + tid) * 64;
    float y0 = 0.f;
    for (int k = 0; k < 63; ++k) y0 += exp_arr[k] * row[1 + k];
    y0 = y0 * 0.04f + (1.f - __expf(-2.52f)) * row[0];  // GEOMETRIC_SUM
    xreg = row[63];
    yreg = y0;
    rreg = 0.f;
  }
  const float b30 = b3[0], b31 = b3[1];

  // W1 resident in registers: w1r[p][mt] = fragment (pan=p, fb=wv*4+mt)
  bf16x8 w1r[2][4];
#pragma unroll
  for (int p = 0; p < 2; ++p)
#pragma unroll
    for (int mt = 0; mt < 4; ++mt)
      w1r[p][mt] = *(const bf16x8*)(wp + (((size_t)p * 32 + wv * 4 + mt) * 64 + lane) * 8);

  // Prime the W2 register pipeline: wcur = panel 2 (first W2 K-block)
  bf16x8 wcur[4], wnxt[4];
#pragma unroll
  for (int mt = 0; mt < 4; ++mt)
    wcur[mt] = *(const bf16x8*)(wp + ((2 * 32 + (size_t)(wv * 4 + mt)) * 64 + lane) * 8);

  __syncthreads();

  int hb = 0;
  f32x4 acc[4][4];

#pragma unroll 1
  for (int t = 0; t < NTS; ++t) {
    // ---- dw tile staging every 16 steps ----
    if ((t & 15) == 0) {
      int b = tid >> 3, c = tid & 7;
      f32x2 v = *(const f32x2*)(dw + ((size_t)wg * 64 + b) * NTS + t + c * 2);
      dwL[(c * 2) * 64 + b] = v[0];
      dwL[(c * 2 + 1) * 64 + b] = v[1];
    }

    // ---- Layer 1: acc = W1 @ histT (K=64, 2 panels, all reg-resident) ----
#pragma unroll
    for (int mt = 0; mt < 4; ++mt)
#pragma unroll
      for (int nt = 0; nt < 4; ++nt) acc[mt][nt] = (f32x4){0.f, 0.f, 0.f, 0.f};
    const char* hcur = histC + hb * 8192;
#pragma unroll
    for (int p = 0; p < 2; ++p) {
      bf16x8 bfr[4];
#pragma unroll
      for (int nt = 0; nt < 4; ++nt)
        bfr[nt] = *(const bf16x8*)(hcur + ((p * 4 + nt) * 64 + lane) * 16);
#pragma unroll
      for (int mt = 0; mt < 4; ++mt)
#pragma unroll
        for (int nt = 0; nt < 4; ++nt)
          acc[mt][nt] = __builtin_amdgcn_mfma_f32_16x16x32_bf16(w1r[p][mt], bfr[nt],
                                                                acc[mt][nt], 0, 0, 0);
    }
    // h1 epilogue: relu(+b1) -> bf16 -> h1F fragment order
#pragma unroll
    for (int mt = 0; mt < 4; ++mt) {
      int f0 = wv * 64 + mt * 16 + q * 4;
      int wb = ((f0 >> 5) * 256 + ((f0 >> 3) & 3) * 16 + j) * 16 + (f0 & 7) * 2;
#pragma unroll
      for (int nt = 0; nt < 4; ++nt) {
        bf16x4 pk;
#pragma unroll
        for (int r = 0; r < 4; ++r)
          pk[r] = (short)f2bf(fmaxf(acc[mt][nt][r] + b1L[f0 + r], 0.f));
        *(bf16x4*)(h1C + wb + nt * 1024) = pk;
      }
    }
    __syncthreads();  // (1) h1F + dwL visible

    // ---- Layer 2: 16 K-panels, weights streamed L2->reg, no barriers ----
#pragma unroll
    for (int mt = 0; mt < 4; ++mt)
#pragma unroll
      for (int nt = 0; nt < 4; ++nt) acc[mt][nt] = (f32x4){0.f, 0.f, 0.f, 0.f};
#pragma unroll
    for (int ks = 0; ks < 16; ++ks) {
      {  // prefetch next panel (wraps to panel 2 for the next timestep)
        int pn = (ks == 15) ? 2 : (ks + 3);
#pragma unroll
        for (int mt = 0; mt < 4; ++mt)
          wnxt[mt] = *(const bf16x8*)(wp + (((size_t)pn * 32 + wv * 4 + mt) * 64 + lane) * 8);
      }
      bf16x8 bfr[4];
#pragma unroll
      for (int nt = 0; nt < 4; ++nt)
        bfr[nt] = *(const bf16x8*)(h1C + ((ks * 4 + nt) * 64 + lane) * 16);
#pragma unroll
      for (int mt = 0; mt < 4; ++mt)
#pragma unroll
        for (int nt = 0; nt < 4; ++nt)
          acc[mt][nt] = __builtin_amdgcn_mfma_f32_16x16x32_bf16(wcur[mt], bfr[nt],
                                                                acc[mt][nt], 0, 0, 0);
#pragma unroll
      for (int mt = 0; mt < 4; ++mt) wcur[mt] = wnxt[mt];
    }

    // ---- Layer 3 folded: pi partials + cross-lane reduce ----
#pragma unroll
    for (int nt = 0; nt < 4; ++nt) {
      float p0a = 0.f, p1a = 0.f;
#pragma unroll
      for (int mt = 0; mt < 4; ++mt) {
        int f0 = wv * 64 + mt * 16 + q * 4;
#pragma unroll
        for (int r = 0; r < 4; ++r) {
          float v = fmaxf(acc[mt][nt][r] + b2L[f0 + r], 0.f);
          p0a += v * w3L[(f0 + r) * 2];
          p1a += v * w3L[(f0 + r) * 2 + 1];
        }
      }
      p0a += __shfl_xor(p0a, 16); p0a += __shfl_xor(p0a, 32);
      p1a += __shfl_xor(p1a, 16); p1a += __shfl_xor(p1a, 32);
      if (q == 0) {
        int b = nt * 16 + j;
        piL[(wv * 64 + b) * 2] = p0a;
        piL[(wv * 64 + b) * 2 + 1] = p1a;
      }
    }
    __syncthreads();  // (2) piL visible

    // ---- dynamics (wave 0) ----
    if (tid < 64) {
      float z0 = b30, z1 = b31;
#pragma unroll
      for (int w = 0; w < 8; ++w) {
        z0 += piL[(w * 64 + tid) * 2];
        z1 += piL[(w * 64 + tid) * 2 + 1];
      }
      float pi0 = 2.f / (1.f + __expf(-z0));
      float pi1 = 2.f / (1.f + __expf(-z1));
      float x = xreg, y = yreg;
      float disc = __expf(-0.004f * (float)t);
      float rv = fmaxf(pi0 * x, 0.f) + 1e-6f;
      rreg += (__logf(rv) * disc - fmaxf(-x, 0.f) * 100.f) * 0.04f;
      float dwv = dwL[(t & 15) * 64 + tid];
      float dxv = (0.06f * pi1 - pi0 + 0.02f) * x + 0.02f * y;
      float xn = x + dxv * 0.04f + 0.2f * x * pi1 * dwv;
      yreg = y * 0.960789439152323f + xn * 0.04f;   // exp(-DT*LAMBD)
      xreg = xn;
      xnbL[tid] = f2bf(xn);
    }
    __syncthreads();  // (3) xnbL visible

    // ---- hist shift in fragment order: new[b][k] = old[b][k+1], [63]=x_new ----
    {
      const char* hc = histC + hb * 8192;
      char* hn = histC + (hb ^ 1) * 8192;
      int ntp = tid >> 6;
      int pIdx = ntp >> 2;            // 0 or 1
      int b = (ntp & 3) * 16 + j;
      bf16x8 own = *(const bf16x8*)(hc + tid * 16);
      unsigned short last;
      if (q == 3 && pIdx == 1) {
        last = xnbL[b];
      } else {
        int idx2 = (q < 3) ? tid + 16 : tid + 208;  // next k-block, same (b)
        bf16x8 nx = *(const bf16x8*)(hc + idx2 * 16);
        last = (unsigned short)nx[0];
      }
      bf16x8 nw;
#pragma unroll
      for (int e = 0; e < 7; ++e) nw[e] = own[e + 1];
      nw[7] = (short)last;
      *(bf16x8*)(hn + tid * 16) = nw;
    }
    hb ^= 1;
    __syncthreads();  // (4) histF[next] visible
  }

  if (tid < 64) {
    float rw = rreg + __logf(fmaxf(xreg + 0.5f * yreg, 0.f) + 1e-6f) * 10.f * __expf(-1.024f);
    rw -= fmaxf(-xreg, 0.f) * 100.f;
    out[(size_t)wg * 64 + tid] = -rw;
  }
}

extern "C" void kernel_launch(void* const* d_in, const int* in_sizes, int n_in,
                              void* d_out, int out_size, void* d_ws, size_t ws_size,
                              hipStream_t stream) {
  const float* dw      = (const float*)d_in[0];
  const float* x_init  = (const float*)d_in[1];
  const float* exp_arr = (const float*)d_in[2];
  const float* W1      = (const float*)d_in[3];
  const float* b1      = (const float*)d_in[4];
  const float* W2      = (const float*)d_in[5];
  const float* b2      = (const float*)d_in[6];
  const float* W3      = (const float*)d_in[7];
  const float* b3      = (const float*)d_in[8];
  unsigned short* wp = (unsigned short*)d_ws;  // needs 576KB
  float* out = (float*)d_out;

  (void)hipFuncSetAttribute((const void*)po_fused,
                            hipFuncAttributeMaxDynamicSharedMemorySize, 160 * 1024);

  prep_weights<<<1152, 256, 0, stream>>>(W1, W2, wp);
  po_fused<<<256, 512, 98432, stream>>>(dw, x_init, exp_arr, b1, b2, W3, b3, wp, out);
}

// Round 4
// 3289.743 us; speedup vs baseline: 1.4779x; 1.4031x over previous
//
#include <hip/hip_runtime.h>
#include <stdint.h>
#include <stddef.h>

#define NTS 256

typedef short bf16x8 __attribute__((ext_vector_type(8)));
typedef short bf16x4 __attribute__((ext_vector_type(4)));
typedef float f32x4 __attribute__((ext_vector_type(4)));
typedef float f32x2 __attribute__((ext_vector_type(2)));

__device__ __forceinline__ unsigned short f2bf(float f) {
  union { float f; unsigned u; } c; c.f = f;
  unsigned u = c.u;
  u += 0x7fffu + ((u >> 16) & 1u);   // round-to-nearest-even
  return (unsigned short)(u >> 16);
}

// Fragment-ordered weight panels (UNCHANGED from r3):
// wpF[pan(18)][fb(32)][lane(64)][e(8)] bf16
//   pan 0..1 -> W1 K-blocks, pan 2..17 -> W2 K-blocks (pan-2)
//   value = W[k = pank*32 + (lane>>4)*8 + e][f = fb*16 + (lane&15)]
__global__ __launch_bounds__(256) void prep_weights(const float* __restrict__ W1,
                                                    const float* __restrict__ W2,
                                                    unsigned short* __restrict__ wp) {
  int gid = blockIdx.x * 256 + threadIdx.x;
  if (gid >= 294912) return;
  int e = gid & 7, lane = (gid >> 3) & 63, fb = (gid >> 9) & 31, pan = gid >> 14;
  int q = lane >> 4, j = lane & 15, f = fb * 16 + j;
  float v;
  if (pan < 2) v = W1[(pan * 32 + q * 8 + e) * 512 + f];
  else         v = W2[((pan - 2) * 32 + q * 8 + e) * 512 + f];
  wp[gid] = f2bf(v);
}

// DMA one panel's per-wave slice (4KB) into LDS: dst = base + wv*4096,
// layout matches fragment order exactly (lane*16 HW pattern == [lane][16B]).
__device__ __forceinline__ void stage_panel(const unsigned short* __restrict__ wp,
                                            int pan, char* dst_base, int wv, int lane) {
#pragma unroll
  for (int i = 0; i < 4; ++i) {
    const unsigned short* g = wp + (size_t)pan * 16384 + (wv * 4 + i) * 512 + lane * 8;
    char* l = dst_base + wv * 4096 + i * 1024;  // HW adds lane*16
    __builtin_amdgcn_global_load_lds((const __attribute__((address_space(1))) void*)g,
                                     (__attribute__((address_space(3))) void*)l,
                                     16, 0, 0);
  }
}

// LDS map (bytes):
//   [0,      65536)  wbuf: 2 x 32KB panel double-buffer [fb(32)][lane(64)][16B]
//   [65536, 131072)  h1F  [ks(16)][nt(4)][lane(64)][16B]
//   [131072,139264)  histF [p(2)][nt(4)][lane(64)][16B]  (single buffer, in-place shift)
//   [139264,143360)  piL  [8 waves][64 b][2] f32
//   [143360,147456)  dwL  [k(16)][b(64)] f32
//   [147456,147584)  xnbL bf16[64]
//   [147584,149632)  b1L f32[512]
//   [149632,151680)  b2L f32[512]
//   [151680,155776)  w3L f32[512][2]
__global__ __launch_bounds__(512, 2) void po_fused(
    const float* __restrict__ dw, const float* __restrict__ x_init,
    const float* __restrict__ exp_arr, const float* __restrict__ b1,
    const float* __restrict__ b2, const float* __restrict__ W3,
    const float* __restrict__ b3, const unsigned short* __restrict__ wp,
    float* __restrict__ out) {
  extern __shared__ char smem[];
  char* const wbuf = smem;
  char* const h1C = smem + 65536;
  char* const histC = smem + 131072;
  float* const piL = (float*)(smem + 139264);
  float* const dwL = (float*)(smem + 143360);
  unsigned short* const xnbL = (unsigned short*)(smem + 147456);
  float* const b1L = (float*)(smem + 147584);
  float* const b2L = (float*)(smem + 149632);
  float* const w3L = (float*)(smem + 151680);

  const int tid = threadIdx.x;
  const int lane = tid & 63;
  const int wv = tid >> 6;
  const int q = lane >> 4;
  const int j = lane & 15;
  const int wg = blockIdx.x;

  // ---------------- init ----------------
  b1L[tid] = b1[tid];
  b2L[tid] = b2[tid];
  w3L[tid] = W3[tid];
  w3L[tid + 512] = W3[tid + 512];

  {  // histF fill, fragment order: block tid <-> (p,nt,lane)
    int ntp = tid >> 6;               // p*4+nt
    int p0 = ntp >> 2, nt0 = ntp & 3;
    int b = nt0 * 16 + j, k0 = p0 * 32 + q * 8;
    const float* src = x_init + ((size_t)wg * 64 + b) * 64 + k0;
    bf16x8 v;
#pragma unroll
    for (int e = 0; e < 8; ++e) v[e] = (short)f2bf(src[e]);
    *(bf16x8*)(histC + tid * 16) = v;
  }

  float xreg = 0.f, yreg = 0.f, rreg = 0.f;   // meaningful in wave 0 only
  if (tid < 64) {
    const float* row = x_init + ((size_t)wg * 64 + tid) * 64;
    float y0 = 0.f;
    for (int k = 0; k < 63; ++k) y0 += exp_arr[k] * row[1 + k];
    y0 = y0 * 0.04f + (1.f - __expf(-2.52f)) * row[0];  // GEOMETRIC_SUM
    xreg = row[63];
    yreg = y0;
  }
  const float b30 = b3[0], b31 = b3[1];

  stage_panel(wp, 0, wbuf, wv, lane);  // prologue: W1 panel 0 -> buf0
  __syncthreads();                     // init LDS visible; drains DMA

  f32x4 acc[4][4];

#pragma unroll 1
  for (int t = 0; t < NTS; ++t) {
    // ---- dw tile staging every 16 steps ----
    if ((t & 15) == 0) {
      int b = tid >> 3, c = tid & 7;
      f32x2 v = *(const f32x2*)(dw + ((size_t)wg * 64 + b) * NTS + t + c * 2);
      dwL[(c * 2) * 64 + b] = v[0];
      dwL[(c * 2 + 1) * 64 + b] = v[1];
    }

    // ---- Layer 1 (slots 0..1 of the 18-slot DMA pipeline) ----
#pragma unroll
    for (int mt = 0; mt < 4; ++mt)
#pragma unroll
      for (int nt = 0; nt < 4; ++nt) acc[mt][nt] = (f32x4){0.f, 0.f, 0.f, 0.f};
#pragma unroll
    for (int p = 0; p < 2; ++p) {
      stage_panel(wp, p + 1, wbuf + ((p ^ 1) * 32768), wv, lane);  // next slot
      asm volatile("s_waitcnt vmcnt(4)" ::: "memory");             // slot p landed
      const char* pb = wbuf + p * 32768 + wv * 4096;
      bf16x8 afr[4], bfr[4];
#pragma unroll
      for (int nt = 0; nt < 4; ++nt)
        bfr[nt] = *(const bf16x8*)(histC + ((p * 4 + nt) * 64 + lane) * 16);
#pragma unroll
      for (int mt = 0; mt < 4; ++mt)
        afr[mt] = *(const bf16x8*)(pb + mt * 1024 + lane * 16);
#pragma unroll
      for (int mt = 0; mt < 4; ++mt)
#pragma unroll
        for (int nt = 0; nt < 4; ++nt)
          acc[mt][nt] = __builtin_amdgcn_mfma_f32_16x16x32_bf16(afr[mt], bfr[nt],
                                                                acc[mt][nt], 0, 0, 0);
    }
    // h1 epilogue: relu(+b1) -> bf16 -> h1F fragment order
#pragma unroll
    for (int mt = 0; mt < 4; ++mt) {
      int f0 = wv * 64 + mt * 16 + q * 4;
      int wb = ((f0 >> 5) * 256 + ((f0 >> 3) & 3) * 16 + j) * 16 + (f0 & 7) * 2;
#pragma unroll
      for (int nt = 0; nt < 4; ++nt) {
        bf16x4 pk;
#pragma unroll
        for (int r = 0; r < 4; ++r)
          pk[r] = (short)f2bf(fmaxf(acc[mt][nt][r] + b1L[f0 + r], 0.f));
        *(bf16x4*)(h1C + wb + nt * 1024) = pk;
      }
    }
    __syncthreads();  // (1) h1F + dwL visible (also drains W2k0 DMA)

    // ---- Layer 2: 16 K-panels, barrier-free per-wave DMA pipeline ----
#pragma unroll
    for (int mt = 0; mt < 4; ++mt)
#pragma unroll
      for (int nt = 0; nt < 4; ++nt) acc[mt][nt] = (f32x4){0.f, 0.f, 0.f, 0.f};
#pragma unroll
    for (int ks = 0; ks < 16; ++ks) {
      // stage next slot: W2 k-block ks+1 (wp panel ks+3); at ks=15 wrap to W1p0
      stage_panel(wp, (ks == 15) ? 0 : (ks + 3), wbuf + (((ks + 1) & 1) * 32768), wv, lane);
      asm volatile("s_waitcnt vmcnt(4)" ::: "memory");  // panel ks landed (counted, not 0)
      const char* pb = wbuf + (ks & 1) * 32768 + wv * 4096;
      bf16x8 afr[4], bfr[4];
#pragma unroll
      for (int nt = 0; nt < 4; ++nt)
        bfr[nt] = *(const bf16x8*)(h1C + ((ks * 4 + nt) * 64 + lane) * 16);
#pragma unroll
      for (int mt = 0; mt < 4; ++mt)
        afr[mt] = *(const bf16x8*)(pb + mt * 1024 + lane * 16);
#pragma unroll
      for (int mt = 0; mt < 4; ++mt)
#pragma unroll
        for (int nt = 0; nt < 4; ++nt)
          acc[mt][nt] = __builtin_amdgcn_mfma_f32_16x16x32_bf16(afr[mt], bfr[nt],
                                                                acc[mt][nt], 0, 0, 0);
    }

    // ---- Layer 3 folded: pi partials + cross-lane reduce ----
#pragma unroll
    for (int nt = 0; nt < 4; ++nt) {
      float p0a = 0.f, p1a = 0.f;
#pragma unroll
      for (int mt = 0; mt < 4; ++mt) {
        int f0 = wv * 64 + mt * 16 + q * 4;
#pragma unroll
        for (int r = 0; r < 4; ++r) {
          float v = fmaxf(acc[mt][nt][r] + b2L[f0 + r], 0.f);
          p0a += v * w3L[(f0 + r) * 2];
          p1a += v * w3L[(f0 + r) * 2 + 1];
        }
      }
      p0a += __shfl_xor(p0a, 16); p0a += __shfl_xor(p0a, 32);
      p1a += __shfl_xor(p1a, 16); p1a += __shfl_xor(p1a, 32);
      if (q == 0) {
        int b = nt * 16 + j;
        piL[(wv * 64 + b) * 2] = p0a;
        piL[(wv * 64 + b) * 2 + 1] = p1a;
      }
    }
    __syncthreads();  // (2) piL visible

    // ---- hist-shift pre-read (all threads; overlaps wave0 dynamics) ----
    bf16x8 hown = *(const bf16x8*)(histC + tid * 16);
    int pIdx = (tid >> 8) & 1;     // block index p
    bool fromX = (q == 3) && (pIdx == 1);
    unsigned short hlast = 0;
    if (!fromX) {
      int idx2 = (q < 3) ? tid + 16 : tid + 208;  // next k-block, same b
      hlast = *(const unsigned short*)(histC + idx2 * 16);
    }

    // ---- dynamics (wave 0) ----
    if (tid < 64) {
      float z0 = b30, z1 = b31;
#pragma unroll
      for (int w = 0; w < 8; ++w) {
        z0 += piL[(w * 64 + tid) * 2];
        z1 += piL[(w * 64 + tid) * 2 + 1];
      }
      float pi0 = 2.f / (1.f + __expf(-z0));
      float pi1 = 2.f / (1.f + __expf(-z1));
      float x = xreg, y = yreg;
      float disc = __expf(-0.004f * (float)t);
      float rv = fmaxf(pi0 * x, 0.f) + 1e-6f;
      rreg += (__logf(rv) * disc - fmaxf(-x, 0.f) * 100.f) * 0.04f;
      float dwv = dwL[(t & 15) * 64 + tid];
      float dxv = (0.06f * pi1 - pi0 + 0.02f) * x + 0.02f * y;
      float xn = x + dxv * 0.04f + 0.2f * x * pi1 * dwv;
      yreg = y * 0.960789439152323f + xn * 0.04f;   // exp(-DT*LAMBD)
      xreg = xn;
      xnbL[tid] = f2bf(xn);
    }
    __syncthreads();  // (3) xnbL visible; all pre-reads complete

    // ---- hist shift write (in place) ----
    {
      int b = ((tid >> 6) & 3) * 16 + j;
      bf16x8 nw;
#pragma unroll
      for (int e = 0; e < 7; ++e) nw[e] = hown[e + 1];
      nw[7] = fromX ? (short)xnbL[b] : (short)hlast;
      *(bf16x8*)(histC + tid * 16) = nw;
    }
    __syncthreads();  // (4) histF stable for next L1
  }

  if (tid < 64) {
    float rw = rreg + __logf(fmaxf(xreg + 0.5f * yreg, 0.f) + 1e-6f) * 10.f * __expf(-1.024f);
    rw -= fmaxf(-xreg, 0.f) * 100.f;
    out[(size_t)wg * 64 + tid] = -rw;
  }
}

extern "C" void kernel_launch(void* const* d_in, const int* in_sizes, int n_in,
                              void* d_out, int out_size, void* d_ws, size_t ws_size,
                              hipStream_t stream) {
  const float* dw      = (const float*)d_in[0];
  const float* x_init  = (const float*)d_in[1];
  const float* exp_arr = (const float*)d_in[2];
  const float* W1      = (const float*)d_in[3];
  const float* b1      = (const float*)d_in[4];
  const float* W2      = (const float*)d_in[5];
  const float* b2      = (const float*)d_in[6];
  const float* W3      = (const float*)d_in[7];
  const float* b3      = (const float*)d_in[8];
  unsigned short* wp = (unsigned short*)d_ws;  // needs 576KB
  float* out = (float*)d_out;

  (void)hipFuncSetAttribute((const void*)po_fused,
                            hipFuncAttributeMaxDynamicSharedMemorySize, 160 * 1024);

  prep_weights<<<1152, 256, 0, stream>>>(W1, W2, wp);
  po_fused<<<256, 512, 155776, stream>>>(dw, x_init, exp_arr, b1, b2, W3, b3, wp, out);
}

// Round 5
// 2375.572 us; speedup vs baseline: 2.0466x; 1.3848x over previous
//
#include <hip/hip_runtime.h>
#include <stdint.h>
#include <stddef.h>

#define NTS 256

typedef short bf16x8 __attribute__((ext_vector_type(8)));
typedef short bf16x4 __attribute__((ext_vector_type(4)));
typedef float f32x4 __attribute__((ext_vector_type(4)));
typedef float f32x2 __attribute__((ext_vector_type(2)));

__device__ __forceinline__ unsigned short f2bf(float f) {
  union { float f; unsigned u; } c; c.f = f;
  unsigned u = c.u;
  u += 0x7fffu + ((u >> 16) & 1u);   // round-to-nearest-even
  return (unsigned short)(u >> 16);
}

// Fragment-ordered weight panels (unchanged):
// wpF[pan(18)][fb(32)][lane(64)][e(8)] bf16
//   pan 0..1 -> W1 K-blocks, pan 2..17 -> W2 K-blocks (pan-2)
//   value = W[k = pank*32 + (lane>>4)*8 + e][f = fb*16 + (lane&15)]
__global__ __launch_bounds__(256) void prep_weights(const float* __restrict__ W1,
                                                    const float* __restrict__ W2,
                                                    unsigned short* __restrict__ wp) {
  int gid = blockIdx.x * 256 + threadIdx.x;
  if (gid >= 294912) return;
  int e = gid & 7, lane = (gid >> 3) & 63, fb = (gid >> 9) & 31, pan = gid >> 14;
  int q = lane >> 4, j = lane & 15, f = fb * 16 + j;
  float v;
  if (pan < 2) v = W1[(pan * 32 + q * 8 + e) * 512 + f];
  else         v = W2[((pan - 2) * 32 + q * 8 + e) * 512 + f];
  wp[gid] = f2bf(v);
}

// DMA one panel's per-wave slice (4KB) into LDS (used once, for W1 residency).
__device__ __forceinline__ void stage_panel(const unsigned short* __restrict__ wp,
                                            int pan, char* dst_base, int wv, int lane) {
#pragma unroll
  for (int i = 0; i < 4; ++i) {
    const unsigned short* g = wp + (size_t)pan * 16384 + (wv * 4 + i) * 512 + lane * 8;
    char* l = dst_base + wv * 4096 + i * 1024;  // HW adds lane*16
    __builtin_amdgcn_global_load_lds((const __attribute__((address_space(1))) void*)g,
                                     (__attribute__((address_space(3))) void*)l,
                                     16, 0, 0);
  }
}

// LDS map (bytes):
//   [0,      65536)  w1L: W1 both panels, LDS-resident [pan(2)][fb(32)][lane(64)][16B]
//   [65536, 131072)  h1F [ks(16)][nt(4)][lane(64)][16B]
//   [131072,139264)  histF [p(2)][nt(4)][lane(64)][16B] (in-place shift)
//   [139264,141312)  h0L u32[512]: element-0 of each hist block (conflict-free neighbor read)
//   [141312,145408)  piL [8 waves][64 b][2] f32
//   [145408,149504)  dwL [k(16)][b(64)] f32
//   [149504,149632)  xnbL bf16[64]
//   [149632,151680)  b1L f32[512]
//   [151680,153728)  b2L f32[512]
//   [153728,157824)  w3L f32[512][2]
__global__ __launch_bounds__(512, 2) void po_fused(
    const float* __restrict__ dw, const float* __restrict__ x_init,
    const float* __restrict__ exp_arr, const float* __restrict__ b1,
    const float* __restrict__ b2, const float* __restrict__ W3,
    const float* __restrict__ b3, const unsigned short* __restrict__ wp,
    float* __restrict__ out) {
  extern __shared__ char smem[];
  char* const w1L = smem;
  char* const h1C = smem + 65536;
  char* const histC = smem + 131072;
  unsigned int* const h0L = (unsigned int*)(smem + 139264);
  float* const piL = (float*)(smem + 141312);
  float* const dwL = (float*)(smem + 145408);
  unsigned short* const xnbL = (unsigned short*)(smem + 149504);
  float* const b1L = (float*)(smem + 149632);
  float* const b2L = (float*)(smem + 151680);
  float* const w3L = (float*)(smem + 153728);

  const int tid = threadIdx.x;
  const int lane = tid & 63;
  const int wv = tid >> 6;
  const int q = lane >> 4;
  const int j = lane & 15;
  const int wg = blockIdx.x;

  // ---------------- init ----------------
  b1L[tid] = b1[tid];
  b2L[tid] = b2[tid];
  w3L[tid] = W3[tid];
  w3L[tid + 512] = W3[tid + 512];

  {  // histF fill, fragment order: block tid <-> (p,nt,lane)
    int ntp = tid >> 6;               // p*4+nt
    int p0 = ntp >> 2, nt0 = ntp & 3;
    int b = nt0 * 16 + j, k0 = p0 * 32 + q * 8;
    const float* src = x_init + ((size_t)wg * 64 + b) * 64 + k0;
    bf16x8 v;
#pragma unroll
    for (int e = 0; e < 8; ++e) v[e] = (short)f2bf(src[e]);
    *(bf16x8*)(histC + tid * 16) = v;
    h0L[tid] = (unsigned int)(unsigned short)v[0];
  }

  float xreg = 0.f, yreg = 0.f, rreg = 0.f;   // meaningful in wave 0 only
  if (tid < 64) {
    const float* row = x_init + ((size_t)wg * 64 + tid) * 64;
    float y0 = 0.f;
    for (int k = 0; k < 63; ++k) y0 += exp_arr[k] * row[1 + k];
    y0 = y0 * 0.04f + (1.f - __expf(-2.52f)) * row[0];  // GEOMETRIC_SUM
    xreg = row[63];
    yreg = y0;
  }
  const float b30 = b3[0], b31 = b3[1];

  // W1 -> LDS once (resident for all 256 steps)
  stage_panel(wp, 0, w1L, wv, lane);
  stage_panel(wp, 1, w1L + 32768, wv, lane);

  // W2 direct-load geometry: per-wave fragment base (elements)
  const unsigned short* const wpW2 = wp + 2 * 16384;
  const int wfo = wv * 2048 + lane * 8;     // + mt*512 + pan*16384

  // prime the register pipeline: wA <- W2 panel 0
  bf16x8 wA[4], wB[4];
#pragma unroll
  for (int mt = 0; mt < 4; ++mt)
    wA[mt] = *(const bf16x8*)(wpW2 + wfo + mt * 512);

  __syncthreads();   // drains W1 DMA + init stores

  f32x4 acc[4][4];

#pragma unroll 1
  for (int t = 0; t < NTS; ++t) {
    // ---- dw tile staging every 16 steps ----
    if ((t & 15) == 0) {
      int b = tid >> 3, c = tid & 7;
      f32x2 v = *(const f32x2*)(dw + ((size_t)wg * 64 + b) * NTS + t + c * 2);
      dwL[(c * 2) * 64 + b] = v[0];
      dwL[(c * 2 + 1) * 64 + b] = v[1];
    }

    // ---- Layer 1: W1 (LDS-resident) @ histT ----
#pragma unroll
    for (int mt = 0; mt < 4; ++mt)
#pragma unroll
      for (int nt = 0; nt < 4; ++nt) acc[mt][nt] = (f32x4){0.f, 0.f, 0.f, 0.f};
#pragma unroll
    for (int p = 0; p < 2; ++p) {
      const char* pb = w1L + p * 32768 + wv * 4096;
#pragma unroll
      for (int nt = 0; nt < 4; ++nt) {
        bf16x8 bfr = *(const bf16x8*)(histC + ((p * 4 + nt) * 64 + lane) * 16);
#pragma unroll
        for (int mt = 0; mt < 4; ++mt) {
          bf16x8 afr = *(const bf16x8*)(pb + mt * 1024 + lane * 16);
          acc[mt][nt] = __builtin_amdgcn_mfma_f32_16x16x32_bf16(afr, bfr,
                                                                acc[mt][nt], 0, 0, 0);
        }
      }
    }
    // h1 epilogue: relu(+b1) -> bf16 -> h1F fragment order
#pragma unroll
    for (int mt = 0; mt < 4; ++mt) {
      int f0 = wv * 64 + mt * 16 + q * 4;
      int wb = ((f0 >> 5) * 256 + ((f0 >> 3) & 3) * 16 + j) * 16 + (f0 & 7) * 2;
#pragma unroll
      for (int nt = 0; nt < 4; ++nt) {
        bf16x4 pk;
#pragma unroll
        for (int r = 0; r < 4; ++r)
          pk[r] = (short)f2bf(fmaxf(acc[mt][nt][r] + b1L[f0 + r], 0.f));
        *(bf16x4*)(h1C + wb + nt * 1024) = pk;
      }
    }
    __syncthreads();  // (1) h1F + dwL visible

    // ---- Layer 2: 16 K-panels, weights L2->VGPR, 2-stage pipeline ----
#pragma unroll
    for (int mt = 0; mt < 4; ++mt)
#pragma unroll
      for (int nt = 0; nt < 4; ++nt) acc[mt][nt] = (f32x4){0.f, 0.f, 0.f, 0.f};
    {
      const unsigned short* pb = wpW2;
      const char* h1p = h1C;
#pragma unroll 1
      for (int kk = 0; kk < 8; ++kk) {
        // prefetch odd panel (2kk+1) into wB
#pragma unroll
        for (int mt = 0; mt < 4; ++mt)
          wB[mt] = *(const bf16x8*)(pb + 16384 + wfo + mt * 512);
        // phase 2kk with wA
#pragma unroll
        for (int nt = 0; nt < 4; ++nt) {
          bf16x8 bfr = *(const bf16x8*)(h1p + nt * 1024 + lane * 16);
#pragma unroll
          for (int mt = 0; mt < 4; ++mt)
            acc[mt][nt] = __builtin_amdgcn_mfma_f32_16x16x32_bf16(wA[mt], bfr,
                                                                  acc[mt][nt], 0, 0, 0);
        }
        // prefetch next even panel into wA (wraps to panel 0 for next step)
        {
          const unsigned short* pn = (kk == 7) ? wpW2 : (pb + 32768);
#pragma unroll
          for (int mt = 0; mt < 4; ++mt)
            wA[mt] = *(const bf16x8*)(pn + wfo + mt * 512);
        }
        // phase 2kk+1 with wB
#pragma unroll
        for (int nt = 0; nt < 4; ++nt) {
          bf16x8 bfr = *(const bf16x8*)(h1p + 4096 + nt * 1024 + lane * 16);
#pragma unroll
          for (int mt = 0; mt < 4; ++mt)
            acc[mt][nt] = __builtin_amdgcn_mfma_f32_16x16x32_bf16(wB[mt], bfr,
                                                                  acc[mt][nt], 0, 0, 0);
        }
        pb += 32768;
        h1p += 8192;
      }
    }

    // ---- Layer 3 folded: pi partials + cross-lane reduce ----
#pragma unroll
    for (int nt = 0; nt < 4; ++nt) {
      float p0a = 0.f, p1a = 0.f;
#pragma unroll
      for (int mt = 0; mt < 4; ++mt) {
        int f0 = wv * 64 + mt * 16 + q * 4;
#pragma unroll
        for (int r = 0; r < 4; ++r) {
          float v = fmaxf(acc[mt][nt][r] + b2L[f0 + r], 0.f);
          p0a += v * w3L[(f0 + r) * 2];
          p1a += v * w3L[(f0 + r) * 2 + 1];
        }
      }
      p0a += __shfl_xor(p0a, 16); p0a += __shfl_xor(p0a, 32);
      p1a += __shfl_xor(p1a, 16); p1a += __shfl_xor(p1a, 32);
      if (q == 0) {
        int b = nt * 16 + j;
        piL[(wv * 64 + b) * 2] = p0a;
        piL[(wv * 64 + b) * 2 + 1] = p1a;
      }
    }
    __syncthreads();  // (2) piL visible

    // ---- hist-shift pre-read (overlaps wave0 dynamics) ----
    bf16x8 hown = *(const bf16x8*)(histC + tid * 16);
    int pIdx = (tid >> 8) & 1;
    bool fromX = (q == 3) && (pIdx == 1);
    unsigned short hlast = 0;
    if (!fromX) {
      int idx2 = (q < 3) ? tid + 16 : tid + 208;  // next k-block, same b
      hlast = (unsigned short)h0L[idx2];          // conflict-free word read
    }

    // ---- dynamics (wave 0) ----
    if (tid < 64) {
      float z0 = b30, z1 = b31;
#pragma unroll
      for (int w = 0; w < 8; ++w) {
        z0 += piL[(w * 64 + tid) * 2];
        z1 += piL[(w * 64 + tid) * 2 + 1];
      }
      float pi0 = 2.f / (1.f + __expf(-z0));
      float pi1 = 2.f / (1.f + __expf(-z1));
      float x = xreg, y = yreg;
      float disc = __expf(-0.004f * (float)t);
      float rv = fmaxf(pi0 * x, 0.f) + 1e-6f;
      rreg += (__logf(rv) * disc - fmaxf(-x, 0.f) * 100.f) * 0.04f;
      float dwv = dwL[(t & 15) * 64 + tid];
      float dxv = (0.06f * pi1 - pi0 + 0.02f) * x + 0.02f * y;
      float xn = x + dxv * 0.04f + 0.2f * x * pi1 * dwv;
      yreg = y * 0.960789439152323f + xn * 0.04f;   // exp(-DT*LAMBD)
      xreg = xn;
      xnbL[tid] = f2bf(xn);
    }
    __syncthreads();  // (3) xnbL visible; all pre-reads complete

    // ---- hist shift write (in place) + h0L refresh ----
    {
      int b = ((tid >> 6) & 3) * 16 + j;
      bf16x8 nw;
#pragma unroll
      for (int e = 0; e < 7; ++e) nw[e] = hown[e + 1];
      nw[7] = fromX ? (short)xnbL[b] : (short)hlast;
      *(bf16x8*)(histC + tid * 16) = nw;
      h0L[tid] = (unsigned int)(unsigned short)nw[0];
    }
    __syncthreads();  // (4) histF stable for next L1
  }

  if (tid < 64) {
    float rw = rreg + __logf(fmaxf(xreg + 0.5f * yreg, 0.f) + 1e-6f) * 10.f * __expf(-1.024f);
    rw -= fmaxf(-xreg, 0.f) * 100.f;
    out[(size_t)wg * 64 + tid] = -rw;
  }
}

extern "C" void kernel_launch(void* const* d_in, const int* in_sizes, int n_in,
                              void* d_out, int out_size, void* d_ws, size_t ws_size,
                              hipStream_t stream) {
  const float* dw      = (const float*)d_in[0];
  const float* x_init  = (const float*)d_in[1];
  const float* exp_arr = (const float*)d_in[2];
  const float* W1      = (const float*)d_in[3];
  const float* b1      = (const float*)d_in[4];
  const float* W2      = (const float*)d_in[5];
  const float* b2      = (const float*)d_in[6];
  const float* W3      = (const float*)d_in[7];
  const float* b3      = (const float*)d_in[8];
  unsigned short* wp = (unsigned short*)d_ws;  // needs 576KB
  float* out = (float*)d_out;

  (void)hipFuncSetAttribute((const void*)po_fused,
                            hipFuncAttributeMaxDynamicSharedMemorySize, 160 * 1024);

  prep_weights<<<1152, 256, 0, stream>>>(W1, W2, wp);
  po_fused<<<256, 512, 157824, stream>>>(dw, x_init, exp_arr, b1, b2, W3, b3, wp, out);
}

// Round 8
// 2270.662 us; speedup vs baseline: 2.1412x; 1.0462x over previous
//
#include <hip/hip_runtime.h>
#include <stdint.h>
#include <stddef.h>

#define NTS 256

typedef short bf16x8 __attribute__((ext_vector_type(8)));
typedef short bf16x4 __attribute__((ext_vector_type(4)));
typedef float f32x4 __attribute__((ext_vector_type(4)));
typedef float f32x2 __attribute__((ext_vector_type(2)));

__device__ __forceinline__ unsigned short f2bf(float f) {
  union { float f; unsigned u; } c; c.f = f;
  unsigned u = c.u;
  u += 0x7fffu + ((u >> 16) & 1u);   // round-to-nearest-even (proven r1-r5)
  return (unsigned short)(u >> 16);
}

// Fragment-ordered weight panels (unchanged):
// wpF[pan(18)][fb(32)][lane(64)][e(8)] bf16
//   pan 0..1 -> W1 K-blocks, pan 2..17 -> W2 K-blocks (pan-2)
//   value = W[k = pank*32 + (lane>>4)*8 + e][f = fb*16 + (lane&15)]
__global__ __launch_bounds__(256) void prep_weights(const float* __restrict__ W1,
                                                    const float* __restrict__ W2,
                                                    unsigned short* __restrict__ wp) {
  int gid = blockIdx.x * 256 + threadIdx.x;
  if (gid >= 294912) return;
  int e = gid & 7, lane = (gid >> 3) & 63, fb = (gid >> 9) & 31, pan = gid >> 14;
  int q = lane >> 4, j = lane & 15, f = fb * 16 + j;
  float v;
  if (pan < 2) v = W1[(pan * 32 + q * 8 + e) * 512 + f];
  else         v = W2[((pan - 2) * 32 + q * 8 + e) * 512 + f];
  wp[gid] = f2bf(v);
}

// DMA one panel's per-wave slice (4KB) into LDS (used once, for W1 residency).
__device__ __forceinline__ void stage_panel(const unsigned short* __restrict__ wp,
                                            int pan, char* dst_base, int wv, int lane) {
#pragma unroll
  for (int i = 0; i < 4; ++i) {
    const unsigned short* g = wp + (size_t)pan * 16384 + (wv * 4 + i) * 512 + lane * 8;
    char* l = dst_base + wv * 4096 + i * 1024;  // HW adds lane*16
    __builtin_amdgcn_global_load_lds((const __attribute__((address_space(1))) void*)g,
                                     (__attribute__((address_space(3))) void*)l,
                                     16, 0, 0);
  }
}

// LDS map (bytes):
//   [0,      65536)  w1L: W1 resident [pan(2)][fb(32)][lane(64)][16B]
//   [65536, 131072)  h1C [ks(16)][nt(4)][lane(64)][16B]
//   [131072,139264)  histC [blk(8)][lane(64)][16B] (in-place shift)
//   [139264,143360)  h0L u32[2][512] double-buffered element-0 of each hist block
//   [143360,145408)  p0L f32[8][64]
//   [145408,147456)  p1L f32[8][64]
//   [147456,151552)  dwL f32[16][64]
//   [151552,153600)  b1L f32[512]
//   [153600,155648)  b2L f32[512]
//   [155648,159744)  w3L f32[512][2]
__global__ __launch_bounds__(512, 2) void po_fused(
    const float* __restrict__ dw, const float* __restrict__ x_init,
    const float* __restrict__ exp_arr, const float* __restrict__ b1,
    const float* __restrict__ b2, const float* __restrict__ W3,
    const float* __restrict__ b3, const unsigned short* __restrict__ wp,
    float* __restrict__ out) {
  extern __shared__ char smem[];
  char* const w1L = smem;
  char* const h1C = smem + 65536;
  char* const histC = smem + 131072;
  unsigned int* const h0L = (unsigned int*)(smem + 139264);
  float* const p0L = (float*)(smem + 143360);
  float* const p1L = (float*)(smem + 145408);
  float* const dwL = (float*)(smem + 147456);
  float* const b1L = (float*)(smem + 151552);
  float* const b2L = (float*)(smem + 153600);
  float* const w3L = (float*)(smem + 155648);

  const int tid = threadIdx.x;
  const int lane = tid & 63;
  const int wv = tid >> 6;
  const int q = lane >> 4;
  const int j = lane & 15;
  const int wg = blockIdx.x;

  // ---------------- init ----------------
  b1L[tid] = b1[tid];
  b2L[tid] = b2[tid];
  w3L[tid] = W3[tid];
  w3L[tid + 512] = W3[tid + 512];

  // hist block owned by this thread: block index = wv, within-block (q,j)
  const int b_h = (wv & 3) * 16 + j;        // batch row of this hist block
  {
    const int k0 = (wv >> 2) * 32 + q * 8;
    const float* src = x_init + ((size_t)wg * 64 + b_h) * 64 + k0;
    bf16x8 v;
#pragma unroll
    for (int e = 0; e < 8; ++e) v[e] = (short)f2bf(src[e]);
    *(bf16x8*)(histC + tid * 16) = v;
    h0L[tid] = (unsigned int)(unsigned short)v[0];   // buffer 0 (read at t=0)
  }

  // replicated per-row dynamic state: row = lane (identical in all 8 waves)
  float xreg, yreg, rreg = 0.f;
  {
    const float* row = x_init + ((size_t)wg * 64 + lane) * 64;
    float y0 = 0.f;
    for (int k = 0; k < 63; ++k) y0 += exp_arr[k] * row[1 + k];
    yreg = y0 * 0.04f + (1.f - __expf(-2.52f)) * row[0];  // GEOMETRIC_SUM
    xreg = row[63];
  }
  const float b30 = b3[0], b31 = b3[1];

  // W1 -> LDS once (resident all 256 steps)
  stage_panel(wp, 0, w1L, wv, lane);
  stage_panel(wp, 1, w1L + 32768, wv, lane);

  // W2 direct-load geometry
  const unsigned short* const wpW2 = wp + 32768;
  const int wfo = wv * 2048 + lane * 8;     // + mt*512 (+ panel*16384)

  bf16x8 wA[4], wB[4];
#pragma unroll
  for (int mt = 0; mt < 4; ++mt)
    wA[mt] = *(const bf16x8*)(wpW2 + wfo + mt * 512);

  __syncthreads();   // drains W1 DMA + init LDS stores

  f32x4 acc[4][4];

#pragma unroll 1
  for (int t = 0; t < NTS; ++t) {
    // ---- dw tile staging every 16 steps ----
    if ((t & 15) == 0) {
      int b = tid >> 3, c = tid & 7;
      f32x2 v = *(const f32x2*)(dw + ((size_t)wg * 64 + b) * NTS + t + c * 2);
      dwL[(c * 2) * 64 + b] = v[0];
      dwL[(c * 2 + 1) * 64 + b] = v[1];
    }

    // ---- Layer 1: W1 (LDS) @ histT ----
#pragma unroll
    for (int mt = 0; mt < 4; ++mt)
#pragma unroll
      for (int nt = 0; nt < 4; ++nt) acc[mt][nt] = (f32x4){0.f, 0.f, 0.f, 0.f};
#pragma unroll
    for (int p = 0; p < 2; ++p) {
      const char* pb = w1L + p * 32768 + wv * 4096;
      bf16x8 bfr[4];
#pragma unroll
      for (int nt = 0; nt < 4; ++nt)
        bfr[nt] = *(const bf16x8*)(histC + ((p * 4 + nt) * 64 + lane) * 16);
#pragma unroll
      for (int mt = 0; mt < 4; ++mt) {
        bf16x8 afr = *(const bf16x8*)(pb + mt * 1024 + lane * 16);
#pragma unroll
        for (int nt = 0; nt < 4; ++nt)
          acc[mt][nt] = __builtin_amdgcn_mfma_f32_16x16x32_bf16(afr, bfr[nt],
                                                                acc[mt][nt], 0, 0, 0);
      }
    }
    // h1 epilogue: relu(+b1) -> bf16 (manual RNE f2bf, proven) -> h1C
#pragma unroll
    for (int mt = 0; mt < 4; ++mt) {
      int f0 = wv * 64 + mt * 16 + q * 4;
      f32x4 b1v = *(const f32x4*)(b1L + f0);
      int wb = ((f0 >> 5) * 256 + ((f0 >> 3) & 3) * 16 + j) * 16 + (f0 & 7) * 2;
#pragma unroll
      for (int nt = 0; nt < 4; ++nt) {
        bf16x4 pk;
#pragma unroll
        for (int r = 0; r < 4; ++r)
          pk[r] = (short)f2bf(fmaxf(acc[mt][nt][r] + b1v[r], 0.f));
        *(bf16x4*)(h1C + wb + nt * 1024) = pk;
      }
    }
    __syncthreads();  // (A) h1C + dwL visible

    // ---- Layer 2: 16 K-panels, weights L2->VGPR, 2-stage pipeline ----
#pragma unroll
    for (int mt = 0; mt < 4; ++mt)
#pragma unroll
      for (int nt = 0; nt < 4; ++nt) acc[mt][nt] = (f32x4){0.f, 0.f, 0.f, 0.f};
    {
      const unsigned short* pb = wpW2;
      const char* h1p = h1C;
#pragma unroll 1
      for (int kk = 0; kk < 8; ++kk) {
#pragma unroll
        for (int mt = 0; mt < 4; ++mt)
          wB[mt] = *(const bf16x8*)(pb + 16384 + wfo + mt * 512);
        __builtin_amdgcn_s_setprio(1);
#pragma unroll
        for (int nt = 0; nt < 4; ++nt) {
          bf16x8 bfr = *(const bf16x8*)(h1p + nt * 1024 + lane * 16);
#pragma unroll
          for (int mt = 0; mt < 4; ++mt)
            acc[mt][nt] = __builtin_amdgcn_mfma_f32_16x16x32_bf16(wA[mt], bfr,
                                                                  acc[mt][nt], 0, 0, 0);
        }
        __builtin_amdgcn_s_setprio(0);
        {
          const unsigned short* pn = (kk == 7) ? wpW2 : (pb + 32768);
#pragma unroll
          for (int mt = 0; mt < 4; ++mt)
            wA[mt] = *(const bf16x8*)(pn + wfo + mt * 512);
        }
        __builtin_amdgcn_s_setprio(1);
#pragma unroll
        for (int nt = 0; nt < 4; ++nt) {
          bf16x8 bfr = *(const bf16x8*)(h1p + 4096 + nt * 1024 + lane * 16);
#pragma unroll
          for (int mt = 0; mt < 4; ++mt)
            acc[mt][nt] = __builtin_amdgcn_mfma_f32_16x16x32_bf16(wB[mt], bfr,
                                                                  acc[mt][nt], 0, 0, 0);
        }
        __builtin_amdgcn_s_setprio(0);
        pb += 32768;
        h1p += 8192;
      }
    }

    // ---- Layer 3 folded: hoisted vector bias/W3 loads ----
    {
      float p0a[4] = {0.f, 0.f, 0.f, 0.f};
      float p1a[4] = {0.f, 0.f, 0.f, 0.f};
#pragma unroll
      for (int mt = 0; mt < 4; ++mt) {
        int f0 = wv * 64 + mt * 16 + q * 4;
        f32x4 b2v = *(const f32x4*)(b2L + f0);
        f32x4 w3a = *(const f32x4*)(w3L + f0 * 2);      // [f0](c0,c1) [f0+1](c0,c1)
        f32x4 w3b = *(const f32x4*)(w3L + f0 * 2 + 4);  // [f0+2],[f0+3]
#pragma unroll
        for (int nt = 0; nt < 4; ++nt) {
          float v0 = fmaxf(acc[mt][nt][0] + b2v[0], 0.f);
          float v1 = fmaxf(acc[mt][nt][1] + b2v[1], 0.f);
          float v2 = fmaxf(acc[mt][nt][2] + b2v[2], 0.f);
          float v3 = fmaxf(acc[mt][nt][3] + b2v[3], 0.f);
          p0a[nt] += v0 * w3a[0] + v1 * w3a[2] + v2 * w3b[0] + v3 * w3b[2];
          p1a[nt] += v0 * w3a[1] + v1 * w3a[3] + v2 * w3b[1] + v3 * w3b[3];
        }
      }
#pragma unroll
      for (int nt = 0; nt < 4; ++nt) {
        p0a[nt] += __shfl_xor(p0a[nt], 16);
        p0a[nt] += __shfl_xor(p0a[nt], 32);
        p1a[nt] += __shfl_xor(p1a[nt], 16);
        p1a[nt] += __shfl_xor(p1a[nt], 32);
        if (q == 0) {
          int b = nt * 16 + j;
          p0L[wv * 64 + b] = p0a[nt];
          p1L[wv * 64 + b] = p1a[nt];
        }
      }
    }
    __syncthreads();  // (B) p0L/p1L visible

    // ---- dynamics: replicated on ALL waves (row = lane) ----
    float xn;
    {
      float z0 = b30, z1 = b31;
#pragma unroll
      for (int w = 0; w < 8; ++w) {
        z0 += p0L[w * 64 + lane];
        z1 += p1L[w * 64 + lane];
      }
      float pi0 = 2.f / (1.f + __expf(-z0));
      float pi1 = 2.f / (1.f + __expf(-z1));
      float x = xreg, y = yreg;
      float disc = __expf(-0.004f * (float)t);         // exp(-BETA*DT*t)
      float rv = fmaxf(pi0 * x, 0.f) + 1e-6f;
      rreg += (__logf(rv) * disc - fmaxf(-x, 0.f) * 100.f) * 0.04f;
      float dwv = dwL[(t & 15) * 64 + lane];
      float dxv = (0.06f * pi1 - pi0 + 0.02f) * x + 0.02f * y;
      xn = x + dxv * 0.04f + 0.2f * x * pi1 * dwv;
      yreg = y * 0.960789439152323f + xn * 0.04f;      // exp(-DT*LAMBD)
      xreg = xn;
    }

    // ---- hist shift: ALL shuffles uniform (exec-mask-safe), then select ----
    {
      bf16x8 own = *(const bf16x8*)(histC + tid * 16);
      int e0 = (int)(unsigned short)own[0];
      int nbr = __shfl_down(e0, 16);          // uniform: all 64 lanes execute
      float xb = __shfl(xn, b_h);             // uniform: all 64 lanes execute
      unsigned short xbf = f2bf(xb);          // BUGFIX r6/r7: was inside divergent
                                              // branch -> ds_bpermute from inactive
                                              // source lanes (undefined on CDNA)
      unsigned short last;
      if (q == 3) {
        last = (wv >= 4) ? xbf               // k0+8 == 64 -> append new x
                         : (unsigned short)h0L[(t & 1) * 512 + tid + 208];
      } else {
        last = (unsigned short)nbr;
      }
      bf16x8 nw;
#pragma unroll
      for (int e = 0; e < 7; ++e) nw[e] = own[e + 1];
      nw[7] = (short)last;
      *(bf16x8*)(histC + tid * 16) = nw;
      h0L[((t + 1) & 1) * 512 + tid] = (unsigned int)(unsigned short)nw[0];
    }
    __syncthreads();  // (C) histC + h0L stable for next step
  }

  if (tid < 64) {
    float rw = rreg + __logf(fmaxf(xreg + 0.5f * yreg, 0.f) + 1e-6f) * 10.f * __expf(-1.024f);
    rw -= fmaxf(-xreg, 0.f) * 100.f;
    out[(size_t)wg * 64 + tid] = -rw;
  }
}

extern "C" void kernel_launch(void* const* d_in, const int* in_sizes, int n_in,
                              void* d_out, int out_size, void* d_ws, size_t ws_size,
                              hipStream_t stream) {
  const float* dw      = (const float*)d_in[0];
  const float* x_init  = (const float*)d_in[1];
  const float* exp_arr = (const float*)d_in[2];
  const float* W1      = (const float*)d_in[3];
  const float* b1      = (const float*)d_in[4];
  const float* W2      = (const float*)d_in[5];
  const float* b2      = (const float*)d_in[6];
  const float* W3      = (const float*)d_in[7];
  const float* b3      = (const float*)d_in[8];
  unsigned short* wp = (unsigned short*)d_ws;  // needs 576KB
  float* out = (float*)d_out;

  (void)hipFuncSetAttribute((const void*)po_fused,
                            hipFuncAttributeMaxDynamicSharedMemorySize, 160 * 1024);

  prep_weights<<<1152, 256, 0, stream>>>(W1, W2, wp);
  po_fused<<<256, 512, 159744, stream>>>(dw, x_init, exp_arr, b1, b2, W3, b3, wp, out);
}